// Round 1
// 199.178 us; speedup vs baseline: 1.2848x; 1.2848x over previous
//
#include <hip/hip_runtime.h>
#include <hip/hip_bf16.h>

// GIN: 3x [agg = segment_sum(h[src], dst); r = h + agg; h = relu(r@Wa+ba)@Wb+bb]
// then mean over nodes @ Wout + bout -> [1,16]
//
// R12 (from R9 @ 255us): attack the gather latency chain.
//  - block edge keys (src, ushort) + rowptr staged in LDS: no global loads in
//    the per-iteration address chain; gathers issue after ds_read_u16.
//  - masked batch-8 with dummy zero row (index NNODES): serial drain tail gone.
//  - f32x2 packed accumulation (v_pk_add_f32), 3 VALU/dword vs 4.
//  - mean-pool fused into gin layer 3 (fp32 colsums from MFMA acc, atomicAdd);
//    colsum kernel dropped.
//  - S2b dropped: S3/S4 scan the 196 bucket totals in-block.
//  LDS/block 32.0KB -> 5 blocks/CU, all 782 blocks co-resident. 8 launches.

#define NNODES 50000
#define NEDGES 800000
#define DDIM   64
#define DOUT   16

#define CHUNK  4096
#define NB1    196           // ceil(800000/4096)
#define NBUCK  196           // ceil(50000/256), bucket = dst>>8
#define NBCVT  6251          // cvt blocks: (50000+1)*32 / 256 rounded up
#define NB64   782           // ceil(50000/64), fused-layer blocks

#define KCAP   1408          // staged edges/block (mean 1024, sigma~32; +12 sigma)

typedef unsigned int uint;
typedef unsigned short ushort;
typedef __attribute__((ext_vector_type(8))) short bf16x8;
typedef __attribute__((ext_vector_type(4))) float f32x4;
typedef __attribute__((ext_vector_type(2))) float f32x2;

#define LSTR 72   // LDS row stride in ushorts (144B rows, 16B-aligned)

// fp32 -> bf16 RNE (bit trick)
static __device__ __forceinline__ uint f2bf(float f) {
    uint u = __float_as_uint(f);
    return (u + 0x7fffu + ((u >> 16) & 1u)) >> 16;
}
static __device__ __forceinline__ float bf_lo(uint u) { return __uint_as_float(u << 16); }
static __device__ __forceinline__ float bf_hi(uint u) { return __uint_as_float(u & 0xffff0000u); }

// ---------------- S1: pack keys + per-block bucket hist; tail blocks do cvt ----------------
// cvt also zeroes the dummy row (node index NNODES) of hb.

__global__ __launch_bounds__(256) void sort_hist_cvt_kernel(const int* __restrict__ src,
                                                            const int* __restrict__ dst,
                                                            uint* __restrict__ key,
                                                            int* __restrict__ gh,
                                                            const float2* __restrict__ fin,
                                                            uint* __restrict__ hb, int n) {
    __shared__ int h[NBUCK];
    int blk = blockIdx.x;
    if (blk >= NB1) {
        int i = (blk - NB1) * 256 + threadIdx.x;
        if (i < (NNODES + 1) * 32) {
            uint r = 0u;
            if (i < NNODES * 32) {
                float2 v = fin[i];
                r = f2bf(v.x) | (f2bf(v.y) << 16);
            }
            hb[i] = r;
        }
        return;
    }
    for (int i = threadIdx.x; i < NBUCK; i += 256) h[i] = 0;
    __syncthreads();
    int base = blk * CHUNK;
    int end = base + CHUNK < n ? base + CHUNK : n;
    for (int i = base + threadIdx.x; i < end; i += 256) {
        int d = dst[i];
        key[i] = ((uint)d << 16) | (uint)src[i];
        atomicAdd(&h[d >> 8], 1);
    }
    __syncthreads();
    for (int i = threadIdx.x; i < NBUCK; i += 256) gh[blk * NBUCK + i] = h[i];
}

// ---------------- S2a: per-bucket scan over the 196 chunk counts (+ zero part) ----------------

__global__ __launch_bounds__(256) void sort_offsets_a_kernel(const int* __restrict__ gh,
                                                             int* __restrict__ offraw,
                                                             int* __restrict__ tot,
                                                             float* __restrict__ part) {
    __shared__ int s[256];
    int b = blockIdx.x;
    int i = threadIdx.x;
    if (b == 0 && i < 64) part[i] = 0.f;
    int v = (i < NB1) ? gh[i * NBUCK + b] : 0;
    s[i] = v;
    __syncthreads();
    for (int off = 1; off < 256; off <<= 1) {
        int add = (i >= off) ? s[i - off] : 0;
        __syncthreads();
        s[i] += add;
        __syncthreads();
    }
    if (i < NB1) offraw[i * NBUCK + b] = s[i] - v;   // exclusive within bucket
    if (i == 255) tot[b] = s[255];
}

// ---------------- S3: partition into coarse buckets (bucket bases scanned in-block) ----------------

__global__ __launch_bounds__(256) void sort_scatter1_kernel(const uint* __restrict__ key,
                                                            const int* __restrict__ offraw,
                                                            const int* __restrict__ tot,
                                                            uint* __restrict__ out, int n) {
    __shared__ int s[256];
    __shared__ int cur[NBUCK];
    int blk = blockIdx.x;
    int i = threadIdx.x;
    int v = (i < NBUCK) ? tot[i] : 0;
    s[i] = v;
    __syncthreads();
    for (int off = 1; off < 256; off <<= 1) {
        int add = (i >= off) ? s[i - off] : 0;
        __syncthreads();
        s[i] += add;
        __syncthreads();
    }
    if (i < NBUCK) cur[i] = (s[i] - v) + offraw[blk * NBUCK + i];
    __syncthreads();
    int base = blk * CHUNK;
    int end = base + CHUNK < n ? base + CHUNK : n;
    for (int j = base + threadIdx.x; j < end; j += 256) {
        uint k = key[j];
        int pos = atomicAdd(&cur[k >> 24], 1);   // k>>24 == dst>>8
        out[pos] = k;
    }
}

// ---------------- S4: per-bucket counting sort by dst&255; emits rowptr ----------------

__global__ __launch_bounds__(256) void sort_bucket_kernel(const uint* __restrict__ in,
                                                          const int* __restrict__ tot,
                                                          int* __restrict__ rowptr,
                                                          uint* __restrict__ out) {
    __shared__ int s[256];
    __shared__ int h[256];
    __shared__ int cur[256];
    __shared__ int slohi[2];
    int b = blockIdx.x;
    int t = threadIdx.x;
    int v = (t < NBUCK) ? tot[t] : 0;
    s[t] = v;
    __syncthreads();
    for (int off = 1; off < 256; off <<= 1) {
        int add = (t >= off) ? s[t - off] : 0;
        __syncthreads();
        s[t] += add;
        __syncthreads();
    }
    if (t == b) { slohi[0] = s[t] - v; slohi[1] = s[t]; }
    h[t] = 0;
    __syncthreads();
    int lo = slohi[0], hi = slohi[1];
    for (int i = lo + t; i < hi; i += 256)
        atomicAdd(&h[(in[i] >> 16) & 255], 1);
    __syncthreads();
    if (t == 0) {
        int run = lo;
        for (int i = 0; i < 256; i++) { cur[i] = run; run += h[i]; }
    }
    __syncthreads();
    int node = (b << 8) + t;
    if (node < NNODES) rowptr[node] = cur[t];
    if (b == NBUCK - 1 && t == 0) rowptr[NNODES] = NEDGES;
    __syncthreads();   // rowptr reads of cur[] before scatter mutates it
    for (int i = lo + t; i < hi; i += 256) {
        uint k = in[i];
        int pos = atomicAdd(&cur[(k >> 16) & 255], 1);
        out[pos] = k;
    }
}

// ---------------- fused GIN layer ----------------
// 64 nodes/block, 4 waves; wave w owns rows 16w..16w+15. Edge src indices and
// rowptr staged in LDS during the weight-staging phase -> single barrier, then
// everything wave-private. Gather: masked batch-8 (dummy row NNODES is zero),
// no sequential tail. part != nullptr (layer 3): fp32 column sums reduced and
// atomically added into part[64].

#define ACC4(vv) do { f32x2 u_;                                   \
    u_.x = bf_lo((vv).x); u_.y = bf_hi((vv).x); c0 += u_;         \
    u_.x = bf_lo((vv).y); u_.y = bf_hi((vv).y); c1 += u_;         \
    u_.x = bf_lo((vv).z); u_.y = bf_hi((vv).z); c2 += u_;         \
    u_.x = bf_lo((vv).w); u_.y = bf_hi((vv).w); c3 += u_; } while (0)

__global__ __launch_bounds__(256) void gin_layer_kernel(const uint4* __restrict__ h128,
                                                        const int* __restrict__ rowptr,
                                                        const uint* __restrict__ skey,
                                                        const float* __restrict__ Wa,
                                                        const float* __restrict__ ba,
                                                        const float* __restrict__ Wb,
                                                        const float* __restrict__ bb,
                                                        uint4* __restrict__ out128,
                                                        float* __restrict__ part, int n) {
    __shared__ ushort sW1[64 * LSTR];   // Wa^T: [n][k]
    __shared__ ushort sW2[64 * LSTR];   // Wb^T: [n][k]
    __shared__ ushort sX[64 * LSTR];    // r tile -> hidden tile -> output staging
    __shared__ float sba[64], sbb[64];
    __shared__ ushort sSrc[KCAP + 8];   // staged src indices (+8 slack for masked reads)
    __shared__ int sRP[65];             // staged rowptr[node0..node0+64]
    __shared__ float pool[256];         // layer-3 column partial sums (4 waves x 64)

    int t = threadIdx.x;
    int node0 = blockIdx.x * 64;

    for (int i = t; i < 4096; i += 256) {
        int k = i >> 6, nn = i & 63;
        sW1[nn * LSTR + k] = (ushort)f2bf(Wa[i]);
        sW2[nn * LSTR + k] = (ushort)f2bf(Wb[i]);
    }
    if (t < 64) { sba[t] = ba[t]; sbb[t] = bb[t]; }
    if (t < 65) {
        int idx = node0 + t;
        sRP[t] = rowptr[idx < n ? idx : n];
    }
    if (blockIdx.x == 0 && t < 8) {     // zero dummy row of this layer's output
        uint4 z; z.x = 0; z.y = 0; z.z = 0; z.w = 0;
        out128[(size_t)NNODES * 8 + t] = z;
    }
    int eBase = rowptr[node0];
    int vEnd = node0 + 64 < n ? node0 + 64 : n;
    int nE = rowptr[vEnd] - eBase;
    int nS = nE < KCAP ? nE : KCAP;
    for (int i = t; i < nS; i += 256) sSrc[i] = (ushort)skey[eBase + i];
    __syncthreads();   // the only barrier: weights/keys/rowptr visible

    int lane = t & 63;
    int w = t >> 6;
    int m0 = w * 16;
    int g = lane >> 3;       // group 0..7
    uint p = (uint)(lane & 7);   // uint4 index (dims 8p..8p+7)

#pragma unroll
    for (int s = 0; s < 2; s++) {
        int row = m0 + 8 * s + g;
        int v = node0 + row;
        if (v < n) {
            f32x2 c0 = {0.f, 0.f}, c1 = {0.f, 0.f}, c2 = {0.f, 0.f}, c3 = {0.f, 0.f};
            uint4 su = h128[(uint)v * 8u + p];
            ACC4(su);
            int e0r = sRP[row], e1r = sRP[row + 1];
            for (int e = e0r; e < e1r; e += 8) {
                int eo = e - eBase;
                uint k0 = sSrc[eo + 0];
                uint k1 = (e + 1 < e1r) ? (uint)sSrc[eo + 1] : 50000u;
                uint k2 = (e + 2 < e1r) ? (uint)sSrc[eo + 2] : 50000u;
                uint k3 = (e + 3 < e1r) ? (uint)sSrc[eo + 3] : 50000u;
                uint k4 = (e + 4 < e1r) ? (uint)sSrc[eo + 4] : 50000u;
                uint k5 = (e + 5 < e1r) ? (uint)sSrc[eo + 5] : 50000u;
                uint k6 = (e + 6 < e1r) ? (uint)sSrc[eo + 6] : 50000u;
                uint k7 = (e + 7 < e1r) ? (uint)sSrc[eo + 7] : 50000u;
                uint4 v0 = h128[k0 * 8u + p];
                uint4 v1 = h128[k1 * 8u + p];
                uint4 v2 = h128[k2 * 8u + p];
                uint4 v3 = h128[k3 * 8u + p];
                uint4 v4 = h128[k4 * 8u + p];
                uint4 v5 = h128[k5 * 8u + p];
                uint4 v6 = h128[k6 * 8u + p];
                uint4 v7 = h128[k7 * 8u + p];
                ACC4(v0); ACC4(v1); ACC4(v2); ACC4(v3);
                ACC4(v4); ACC4(v5); ACC4(v6); ACC4(v7);
            }
            uint4 o;
            o.x = f2bf(c0.x) | (f2bf(c0.y) << 16);
            o.y = f2bf(c1.x) | (f2bf(c1.y) << 16);
            o.z = f2bf(c2.x) | (f2bf(c2.y) << 16);
            o.w = f2bf(c3.x) | (f2bf(c3.y) << 16);
            *(uint4*)&sX[row * LSTR + (int)p * 8] = o;
        }
    }
    // no barrier: rows m0..m0+15 are wave-private from here on

    // ---- MFMA MLP (layouts verified learn_hip m89/m91)
    int mc = lane & 15;
    int quad = lane >> 4;

    bf16x8 xa0 = *(const bf16x8*)&sX[(m0 + mc) * LSTR + quad * 8];
    bf16x8 xa1 = *(const bf16x8*)&sX[(m0 + mc) * LSTR + 32 + quad * 8];
    ushort hreg[16];
#pragma unroll
    for (int c = 0; c < 4; c++) {
        bf16x8 b0 = *(const bf16x8*)&sW1[(c * 16 + mc) * LSTR + quad * 8];
        bf16x8 b1 = *(const bf16x8*)&sW1[(c * 16 + mc) * LSTR + 32 + quad * 8];
        f32x4 acc = {0.f, 0.f, 0.f, 0.f};
        acc = __builtin_amdgcn_mfma_f32_16x16x32_bf16(xa0, b0, acc, 0, 0, 0);
        acc = __builtin_amdgcn_mfma_f32_16x16x32_bf16(xa1, b1, acc, 0, 0, 0);
        int col = c * 16 + mc;
        float bias = sba[col];
#pragma unroll
        for (int r = 0; r < 4; r++)
            hreg[c * 4 + r] = (ushort)f2bf(fmaxf(acc[r] + bias, 0.f));
    }
#pragma unroll
    for (int c = 0; c < 4; c++) {
        int col = c * 16 + mc;
#pragma unroll
        for (int r = 0; r < 4; r++)
            sX[(m0 + quad * 4 + r) * LSTR + col] = hreg[c * 4 + r];
    }

    bool rok[4];
#pragma unroll
    for (int r = 0; r < 4; r++) rok[r] = (node0 + m0 + quad * 4 + r) < n;
    float csum[4] = {0.f, 0.f, 0.f, 0.f};

    bf16x8 ha0 = *(const bf16x8*)&sX[(m0 + mc) * LSTR + quad * 8];
    bf16x8 ha1 = *(const bf16x8*)&sX[(m0 + mc) * LSTR + 32 + quad * 8];
#pragma unroll
    for (int c = 0; c < 4; c++) {
        bf16x8 b0 = *(const bf16x8*)&sW2[(c * 16 + mc) * LSTR + quad * 8];
        bf16x8 b1 = *(const bf16x8*)&sW2[(c * 16 + mc) * LSTR + 32 + quad * 8];
        f32x4 acc = {0.f, 0.f, 0.f, 0.f};
        acc = __builtin_amdgcn_mfma_f32_16x16x32_bf16(ha0, b0, acc, 0, 0, 0);
        acc = __builtin_amdgcn_mfma_f32_16x16x32_bf16(ha1, b1, acc, 0, 0, 0);
        int col = c * 16 + mc;
        float bias = sbb[col];
#pragma unroll
        for (int r = 0; r < 4; r++) {
            float val = acc[r] + bias;
            hreg[c * 4 + r] = (ushort)f2bf(val);
            csum[c] += rok[r] ? val : 0.f;   // NaN-safe masking (select, not mul)
        }
    }
#pragma unroll
    for (int c = 0; c < 4; c++) {
        int col = c * 16 + mc;
#pragma unroll
        for (int r = 0; r < 4; r++)
            sX[(m0 + quad * 4 + r) * LSTR + col] = hreg[c * 4 + r];
    }

    // output: wave-private rows, 2 x uint4 per lane
#pragma unroll
    for (int i = 0; i < 2; i++) {
        int idx = i * 64 + lane;          // 0..127
        int row16 = idx >> 3, q = idx & 7;
        int row = m0 + row16;
        int gr = node0 + row;
        if (gr < n) out128[(size_t)gr * 8 + q] = *(const uint4*)&sX[row * LSTR + q * 8];
    }

    // ---- fused mean-pool partial (layer 3 only): fp32 colsums -> part[64]
    if (part) {
#pragma unroll
        for (int c = 0; c < 4; c++) {
            csum[c] += __shfl_xor(csum[c], 16);
            csum[c] += __shfl_xor(csum[c], 32);
        }
        if (quad == 0) {
#pragma unroll
            for (int c = 0; c < 4; c++) pool[w * 64 + c * 16 + mc] = csum[c];
        }
        __syncthreads();
        if (t < 64) {
            float s4 = pool[t] + pool[64 + t] + pool[128 + t] + pool[192 + t];
            atomicAdd(&part[t], s4);
        }
    }
}

// ---------------- final linear ----------------

__global__ __launch_bounds__(64) void final_kernel(const float* __restrict__ part,
                                                   const float* __restrict__ Wout,
                                                   const float* __restrict__ bout,
                                                   float* __restrict__ out) {
    __shared__ float cs[64];
    int t = threadIdx.x;
    cs[t] = part[t] * (1.0f / (float)NNODES);
    __syncthreads();
    if (t < DOUT) {
        float o = bout[t];
        for (int d = 0; d < DDIM; d++) o += cs[d] * Wout[d * DOUT + t];
        out[t] = o;
    }
}

// ---------------- launch ----------------

extern "C" void kernel_launch(void* const* d_in, const int* in_sizes, int n_in,
                              void* d_out, int out_size, void* d_ws, size_t ws_size,
                              hipStream_t stream) {
    const float* features = (const float*)d_in[0];
    const int*   src      = (const int*)d_in[1];
    const int*   dst      = (const int*)d_in[2];
    const float* W0a = (const float*)d_in[3];  const float* b0a = (const float*)d_in[4];
    const float* W0b = (const float*)d_in[5];  const float* b0b = (const float*)d_in[6];
    const float* W1a = (const float*)d_in[7];  const float* b1a = (const float*)d_in[8];
    const float* W1b = (const float*)d_in[9];  const float* b1b = (const float*)d_in[10];
    const float* W2a = (const float*)d_in[11]; const float* b2a = (const float*)d_in[12];
    const float* W2b = (const float*)d_in[13]; const float* b2b = (const float*)d_in[14];
    const float* Wout = (const float*)d_in[15]; const float* bout = (const float*)d_in[16];
    float* out = (float*)d_out;

    // workspace layout (16B-aligned segments)
    int* gh     = (int*)d_ws;                // [38416]
    int* offraw = gh + 38416;                // [38416]
    int* tot    = offraw + 38416;            // [256]
    int* rowptr = tot + 256;                 // [50001] -> pad 50016
    uint* keybuf = (uint*)(rowptr + 50016);  // [800000] (final sorted edge list)
    uint* buf2   = keybuf + 800000;          // [800000] (pass-1 partitioned)
    uint* hb0    = buf2 + 800000;            // bf16 h ping [(50000+1)*32]
    uint* hb1    = hb0 + (NNODES + 1) * 32;  // bf16 h pong
    float* part  = (float*)(hb1 + (NNODES + 1) * 32); // [64]

    // edge sort (+ feature cvt & dummy-row zero fused into S1's tail blocks)
    sort_hist_cvt_kernel<<<NB1 + NBCVT, 256, 0, stream>>>(src, dst, keybuf, gh,
                                                          (const float2*)features, hb0, NEDGES);
    sort_offsets_a_kernel<<<NBUCK, 256, 0, stream>>>(gh, offraw, tot, part);
    sort_scatter1_kernel<<<NB1, 256, 0, stream>>>(keybuf, offraw, tot, buf2, NEDGES);
    sort_bucket_kernel<<<NBUCK, 256, 0, stream>>>(buf2, tot, rowptr, keybuf);

    // 3 fused GIN layers (last one also accumulates the mean-pool partials)
    gin_layer_kernel<<<NB64, 256, 0, stream>>>((const uint4*)hb0, rowptr, keybuf,
                                               W0a, b0a, W0b, b0b, (uint4*)hb1, nullptr, NNODES);
    gin_layer_kernel<<<NB64, 256, 0, stream>>>((const uint4*)hb1, rowptr, keybuf,
                                               W1a, b1a, W1b, b1b, (uint4*)hb0, nullptr, NNODES);
    gin_layer_kernel<<<NB64, 256, 0, stream>>>((const uint4*)hb0, rowptr, keybuf,
                                               W2a, b2a, W2b, b2b, (uint4*)hb1, part, NNODES);

    // final linear
    final_kernel<<<1, 64, 0, stream>>>(part, Wout, bout, out);
}